// Round 10
// baseline (666.753 us; speedup 1.0000x reference)
//
#include <hip/hip_runtime.h>

typedef unsigned short u16;
typedef __attribute__((ext_vector_type(8))) short bf16x8;
typedef __attribute__((ext_vector_type(4))) float f32x4;

#define K_CB  1024
#define N_ROWS 131072
#define NUMEL (N_ROWS * 128)
#define TAU2 6.0e-4f
#define SMALLCAP 32768
#define FULLCAP  32768

__device__ __forceinline__ u16 f2bf(float x) {
    union { float f; unsigned int u; } a; a.f = x;
    unsigned int r = a.u + 0x7fffu + ((a.u >> 16) & 1u);
    return (u16)(r >> 16);
}

// ---------- prep codebook: bn + slice-major bf16 HI plane ----------
// Bpl layout: [16 slices][1024 rows][8 bf16]
__global__ void prep_cb_kernel(const float* __restrict__ cb, float* __restrict__ bn,
                               u16* __restrict__ Bpl, int* __restrict__ cnts) {
    int k = blockIdx.x * 256 + threadIdx.x;
    if (blockIdx.x == 0 && threadIdx.x < 2) cnts[threadIdx.x] = 0;
    if (k >= K_CB) return;
    const float4* row4 = reinterpret_cast<const float4*>(cb) + k * 32;
    float s = 0.f;
    #pragma unroll
    for (int i = 0; i < 32; ++i) {
        float4 v = row4[i];
        s = fmaf(v.x, v.x, s); s = fmaf(v.y, v.y, s);
        s = fmaf(v.z, v.z, s); s = fmaf(v.w, v.w, s);
    }
    bn[k] = s;
    const float* rf = cb + k * 128;
    #pragma unroll
    for (int s8 = 0; s8 < 16; ++s8) {
        unsigned int hw[8];
        #pragma unroll
        for (int j = 0; j < 8; ++j) hw[j] = f2bf(rf[s8 * 8 + j]);
        uint4 H;
        H.x = hw[0] | (hw[1] << 16); H.y = hw[2] | (hw[3] << 16);
        H.z = hw[4] | (hw[5] << 16); H.w = hw[6] | (hw[7] << 16);
        *reinterpret_cast<uint4*>(&Bpl[((size_t)s8 * 1024 + k) * 8]) = H;
    }
}

// ---------- fused: transpose+split + hi-plane MFMA GEMM + argmin + candidates + quantize + loss
// 256 threads / 4 waves. A in LDS (one barrier), B fragments direct global->VGPR (L2-hot),
// NO barriers / waits in the K-loop — waves free-run, compiler pipelines B loads.
__launch_bounds__(256, 3)
__global__ void gemm_fused_kernel(const float* __restrict__ in, const float* __restrict__ cb,
                                  const u16* __restrict__ Bpl, const float* __restrict__ bn,
                                  float* __restrict__ out_q, float* __restrict__ idx_out,
                                  uint2* __restrict__ smallL, int* __restrict__ fullL,
                                  int* __restrict__ cnts,
                                  float* __restrict__ deltas, float* __restrict__ partials) {
    __shared__ u16 A_s[16 * 64 * 8];     // 16384 B: [slice][row][8ch] hi plane
    __shared__ float bn_s[K_CB];         // 4096 B
    __shared__ float m_b1s[4 * 64];
    __shared__ float m_b2s[4 * 64];
    __shared__ int   m_i1s[4 * 64];
    __shared__ int   idx_s[64];
    __shared__ float gmin_s[64];
    __shared__ int   flg_s[64];
    __shared__ int   ccnt_s[64];
    __shared__ int   fb_s[64];
    __shared__ int   cand_s[64 * 4];
    __shared__ float red_s[4];

    const int tid = threadIdx.x;
    const int w = tid >> 6, lane = tid & 63, g4 = lane >> 4, l15 = lane & 15;
    const int blk = blockIdx.x, n0 = blk * 64;

    // ---- A staging: gather transpose, bf16-hi split in regs, b128 LDS writes ----
    {
        const int base = (n0 >> 14) * (128 * 16384) + (n0 & 16383);
        for (int i = 0; i < 4; ++i) {
            int p = tid + i * 256;            // 0..1023
            int n = p & 63, s = p >> 6;       // slice 0..15
            const float* g = in + base + (size_t)(s * 8) * 16384 + n;
            unsigned int pw[8];
            #pragma unroll
            for (int j = 0; j < 8; ++j) pw[j] = f2bf(g[(size_t)j * 16384]);
            uint4 H;
            H.x = pw[0] | (pw[1] << 16); H.y = pw[2] | (pw[3] << 16);
            H.z = pw[4] | (pw[5] << 16); H.w = pw[6] | (pw[7] << 16);
            *reinterpret_cast<uint4*>(&A_s[(s * 64 + n) * 8]) = H;
        }
    }
    for (int i = tid; i < K_CB; i += 256) bn_s[i] = bn[i];
    __syncthreads();   // A_s + bn_s ready; the ONLY barrier before the merge phase

    f32x4 acc[4][4];
    const f32x4 zz = {0.f, 0.f, 0.f, 0.f};
    #pragma unroll
    for (int mi = 0; mi < 4; ++mi)
        #pragma unroll
        for (int ni = 0; ni < 4; ++ni) acc[mi][ni] = zz;

    float b1[16], b2[16]; int i1[16];
    #pragma unroll
    for (int sl = 0; sl < 16; ++sl) { b1[sl] = 3.4e38f; b2[sl] = 3.4e38f; i1[sl] = 0; }

    // ---- 16 k-steps, barrier-free: B fragments straight from global (L2) ----
    #pragma unroll
    for (int t = 0; t < 16; ++t) {
        const int chunk = t >> 2, cc = t & 3;
        bf16x8 bfr[4];
        #pragma unroll
        for (int ni = 0; ni < 4; ++ni)
            bfr[ni] = *reinterpret_cast<const bf16x8*>(
                &Bpl[(size_t)((cc * 4 + g4) * 1024 + chunk * 256 + w * 64 + ni * 16 + l15) * 8]);
        bf16x8 af[4];
        #pragma unroll
        for (int mi = 0; mi < 4; ++mi)
            af[mi] = *reinterpret_cast<const bf16x8*>(
                &A_s[((cc * 4 + g4) * 64 + mi * 16 + l15) * 8]);
        #pragma unroll
        for (int mi = 0; mi < 4; ++mi)
            #pragma unroll
            for (int ni = 0; ni < 4; ++ni)
                acc[mi][ni] = __builtin_amdgcn_mfma_f32_16x16x32_bf16(
                    af[mi], bfr[ni], acc[mi][ni], 0, 0, 0);

        if (cc == 3) {
            #pragma unroll
            for (int ni = 0; ni < 4; ++ni) {
                int n = chunk * 256 + w * 64 + ni * 16 + l15;
                float bnv = bn_s[n];
                #pragma unroll
                for (int mi = 0; mi < 4; ++mi) {
                    #pragma unroll
                    for (int r = 0; r < 4; ++r) {
                        float s = fmaf(-2.0f, acc[mi][ni][r], bnv);
                        int sl = mi * 4 + r;
                        float nb2 = fminf(fmaxf(s, b1[sl]), b2[sl]);   // med3: 2nd-best
                        bool lt = s < b1[sl];
                        b1[sl] = lt ? s : b1[sl];
                        i1[sl] = lt ? n : i1[sl];
                        b2[sl] = nb2;
                    }
                    acc[mi][ni] = zz;
                }
            }
        }
    }

    // merge across 16 l15 lanes (per-lane b1/b2/i1 stay intact for emission)
    #pragma unroll
    for (int sl = 0; sl < 16; ++sl) {
        float v1 = b1[sl], v2 = b2[sl]; int ix = i1[sl];
        #pragma unroll
        for (int m = 1; m < 16; m <<= 1) {
            float o1 = __shfl_xor(v1, m, 64);
            int   oi = __shfl_xor(ix, m, 64);
            float o2 = __shfl_xor(v2, m, 64);
            if (o1 < v1 || (o1 == v1 && oi < ix)) { v2 = fminf(v1, o2); v1 = o1; ix = oi; }
            else v2 = fminf(v2, o1);
        }
        if (l15 == 0) {
            int mi = sl >> 2, r = sl & 3;
            int rl = mi * 16 + g4 * 4 + r;
            m_b1s[w * 64 + rl] = v1; m_b2s[w * 64 + rl] = v2; m_i1s[w * 64 + rl] = ix;
        }
    }
    __syncthreads();
    if (tid < 64) {
        float v1 = m_b1s[tid], v2 = m_b2s[tid]; int ix = m_i1s[tid];
        #pragma unroll
        for (int wv = 1; wv < 4; ++wv) {
            float o1 = m_b1s[wv * 64 + tid], o2 = m_b2s[wv * 64 + tid]; int oi = m_i1s[wv * 64 + tid];
            if (o1 < v1 || (o1 == v1 && oi < ix)) { v2 = fminf(v1, o2); v1 = o1; ix = oi; }
            else v2 = fminf(v2, o1);
        }
        idx_s[tid] = ix;
        idx_out[n0 + tid] = (float)ix;
        deltas[n0 + tid] = 0.f;
        gmin_s[tid] = v1;
        flg_s[tid] = (v2 - v1 <= TAU2) ? 1 : 0;
        ccnt_s[tid] = 0;
        fb_s[tid] = 0;
    }
    __syncthreads();

    // candidate emission: each (w,l15) bucket offers its best if within TAU2 of row min
    #pragma unroll
    for (int sl = 0; sl < 16; ++sl) {
        int mi = sl >> 2, r = sl & 3;
        int rl = mi * 16 + g4 * 4 + r;
        if (flg_s[rl]) {
            float g = gmin_s[rl];
            if (b1[sl] - g <= TAU2) {
                int p = atomicAdd(&ccnt_s[rl], 1);
                if (p < 4) cand_s[rl * 4 + p] = i1[sl]; else fb_s[rl] = 1;
            }
            if (b2[sl] - g <= TAU2) fb_s[rl] = 1;  // can't bound 3rd-in-bucket
        }
    }
    __syncthreads();
    if (tid < 64 && flg_s[tid]) {
        int nc = ccnt_s[tid];
        int row = n0 + tid;
        if (!fb_s[tid] && nc >= 2) {
            int p = atomicAdd(&cnts[0], 1);
            if (p < SMALLCAP) {
                unsigned long long key = (unsigned long long)row |
                                         ((unsigned long long)nc << 20);
                for (int j = 0; j < nc; ++j)
                    key |= (unsigned long long)(cand_s[tid * 4 + j] & 1023) << (24 + 10 * j);
                uint2 rec; rec.x = (unsigned)key; rec.y = (unsigned)(key >> 32);
                smallL[p] = rec;
            } else {
                int q = atomicAdd(&cnts[1], 1);
                if (q < FULLCAP) fullL[q] = row;
            }
        } else if (fb_s[tid]) {
            int q = atomicAdd(&cnts[1], 1);
            if (q < FULLCAP) fullL[q] = row;
        }
    }
    __syncthreads();

    // fused quantize + straight-through + loss partial (linear flat layout)
    float acc_l = 0.f;
    const float4* cb4 = reinterpret_cast<const float4*>(cb);
    const float4* in4 = reinterpret_cast<const float4*>(in);
    float4* out4 = reinterpret_cast<float4*>(out_q);
    #pragma unroll
    for (int i = 0; i < 8; ++i) {
        int idx = tid + i * 256;
        int row = idx >> 5;
        int c4 = idx & 31;
        int kq = idx_s[row];
        float4 q = cb4[kq * 32 + c4];
        float4 x = in4[(size_t)(n0 + row) * 32 + c4];
        float4 d, o;
        d.x = q.x - x.x; d.y = q.y - x.y; d.z = q.z - x.z; d.w = q.w - x.w;
        o.x = x.x + d.x; o.y = x.y + d.y; o.z = x.z + d.z; o.w = x.w + d.w;
        out4[(size_t)(n0 + row) * 32 + c4] = o;
        acc_l += d.x * d.x; acc_l += d.y * d.y; acc_l += d.z * d.z; acc_l += d.w * d.w;
    }
    #pragma unroll
    for (int m = 1; m < 64; m <<= 1) acc_l += __shfl_xor(acc_l, m, 64);
    if (lane == 0) red_s[w] = acc_l;
    __syncthreads();
    if (tid == 0) partials[blk] = red_s[0] + red_s[1] + red_s[2] + red_s[3];
}

// ---------- common patch helper (wave-level) ----------
__device__ __forceinline__ void patch_row(const float* __restrict__ in,
                                          const float* __restrict__ cb,
                                          float* __restrict__ idx_out,
                                          float* __restrict__ out_q,
                                          float* __restrict__ deltas,
                                          int row, int k_new, int lane) {
    int k_old = (int)idx_out[row];
    if (k_new == k_old) return;
    if (lane == 0) idx_out[row] = (float)k_new;
    float dd = 0.f;
    if (lane < 32) {
        const float4* in4 = reinterpret_cast<const float4*>(in);
        const float4* cb4 = reinterpret_cast<const float4*>(cb);
        float4* out4 = reinterpret_cast<float4*>(out_q);
        float4 x = in4[(size_t)row * 32 + lane];
        float4 qn = cb4[(size_t)k_new * 32 + lane];
        float4 qo = cb4[(size_t)k_old * 32 + lane];
        float4 dn, dl, o;
        dn.x = qn.x - x.x; dn.y = qn.y - x.y; dn.z = qn.z - x.z; dn.w = qn.w - x.w;
        o.x = x.x + dn.x; o.y = x.y + dn.y; o.z = x.z + dn.z; o.w = x.w + dn.w;
        out4[(size_t)row * 32 + lane] = o;
        dl.x = qo.x - x.x; dl.y = qo.y - x.y; dl.z = qo.z - x.z; dl.w = qo.w - x.w;
        dd = dn.x * dn.x + dn.y * dn.y + dn.z * dn.z + dn.w * dn.w
           - (dl.x * dl.x + dl.y * dl.y + dl.z * dl.z + dl.w * dl.w);
    }
    #pragma unroll
    for (int m = 1; m < 64; m <<= 1) dd += __shfl_xor(dd, m, 64);
    if (lane == 0) deltas[row] = dd;
}

// ---------- small rescore: one wave per record, <=4 candidates, exact arithmetic ----------
__global__ void small_rescore_kernel(const float* __restrict__ in, const float* __restrict__ cb,
                                     const float* __restrict__ bn, const uint2* __restrict__ recs,
                                     const int* __restrict__ cnts, float* __restrict__ idx_out,
                                     float* __restrict__ out_q, float* __restrict__ deltas) {
    __shared__ float xls[4][128];
    const int tid = threadIdx.x, wv = tid >> 6, lane = tid & 63;
    int ns = cnts[0]; if (ns > SMALLCAP) ns = SMALLCAP;
    float* xl = xls[wv];
    for (int f = blockIdx.x * 4 + wv; f < ns; f += gridDim.x * 4) {
        uint2 rc = recs[f];
        unsigned long long key = ((unsigned long long)rc.y << 32) | (unsigned long long)rc.x;
        int row = (int)(key & 131071ull);
        int nc = (int)((key >> 20) & 7ull);
        int ck = (lane < 4) ? (int)((key >> (24 + 10 * lane)) & 1023ull) : 0;
        const float* bp = in + (size_t)(row >> 14) * 2097152 + (row & 16383);
        xl[2 * lane]     = bp[(size_t)(2 * lane) * 16384];
        xl[2 * lane + 1] = bp[(size_t)(2 * lane + 1) * 16384];
        asm volatile("s_waitcnt vmcnt(0) lgkmcnt(0)" ::: "memory");
        float xn = 0.f;
        for (int c = 0; c < 128; ++c) { float v = xl[c]; xn = fmaf(v, v, xn); }
        float s = 3.4e38f; int kk = 0x7fffffff;
        if (lane < nc) {
            const float4* cr = reinterpret_cast<const float4*>(cb + (size_t)ck * 128);
            float dot = 0.f;
            #pragma unroll
            for (int c4 = 0; c4 < 32; ++c4) {
                float4 bv = cr[c4];
                float4 xv = *reinterpret_cast<const float4*>(&xl[c4 * 4]);
                dot = fmaf(xv.x, bv.x, dot); dot = fmaf(xv.y, bv.y, dot);
                dot = fmaf(xv.z, bv.z, dot); dot = fmaf(xv.w, bv.w, dot);
            }
            float t1 = xn + bn[ck];
            s = fmaf(-2.0f, dot, t1);
            kk = ck;
        }
        #pragma unroll
        for (int m = 1; m < 4; m <<= 1) {
            float os = __shfl_xor(s, m, 64);
            int ok = __shfl_xor(kk, m, 64);
            if (os < s || (os == s && ok < kk)) { s = os; kk = ok; }
        }
        int k_new = __shfl(kk, 0, 64);
        patch_row(in, cb, idx_out, out_q, deltas, row, k_new, lane);
    }
}

// ---------- full rescore fallback: one wave per row, exact arithmetic ----------
__global__ void full_rescore_kernel(const float* __restrict__ in, const float* __restrict__ cb,
                                    const float* __restrict__ bn, const int* __restrict__ fullL,
                                    const int* __restrict__ cnts, float* __restrict__ idx_out,
                                    float* __restrict__ out_q, float* __restrict__ deltas) {
    __shared__ float xls[4][128];
    const int tid = threadIdx.x, wv = tid >> 6, lane = tid & 63;
    int nf = cnts[1]; if (nf > FULLCAP) nf = FULLCAP;
    float* xl = xls[wv];
    for (int f = blockIdx.x * 4 + wv; f < nf; f += gridDim.x * 4) {
        int row = fullL[f];
        const float* bp = in + (size_t)(row >> 14) * 2097152 + (row & 16383);
        xl[2 * lane]     = bp[(size_t)(2 * lane) * 16384];
        xl[2 * lane + 1] = bp[(size_t)(2 * lane + 1) * 16384];
        asm volatile("s_waitcnt vmcnt(0) lgkmcnt(0)" ::: "memory");
        float xn = 0.f;
        for (int c = 0; c < 128; ++c) { float v = xl[c]; xn = fmaf(v, v, xn); }
        float best = 3.4e38f; int bi = 0x7fffffff;
        for (int j = 0; j < 16; ++j) {
            int k = j * 64 + lane;
            const float4* cr = reinterpret_cast<const float4*>(cb + (size_t)k * 128);
            float dot = 0.f;
            #pragma unroll
            for (int c4 = 0; c4 < 32; ++c4) {
                float4 bv = cr[c4];
                float4 xv = *reinterpret_cast<const float4*>(&xl[c4 * 4]);
                dot = fmaf(xv.x, bv.x, dot); dot = fmaf(xv.y, bv.y, dot);
                dot = fmaf(xv.z, bv.z, dot); dot = fmaf(xv.w, bv.w, dot);
            }
            float t1 = xn + bn[k];
            float s = fmaf(-2.0f, dot, t1);
            if (s < best || (s == best && k < bi)) { best = s; bi = k; }
        }
        #pragma unroll
        for (int m = 1; m < 64; m <<= 1) {
            float os = __shfl_xor(best, m, 64);
            int ok = __shfl_xor(bi, m, 64);
            if (os < best || (os == best && ok < bi)) { best = os; bi = ok; }
        }
        int k_new = __shfl(bi, 0, 64);
        patch_row(in, cb, idx_out, out_q, deltas, row, k_new, lane);
    }
}

// ---------- deterministic 2-stage loss reduce ----------
__global__ void loss_stage1(const float* __restrict__ partials, const float* __restrict__ deltas,
                            float* __restrict__ part2) {
    __shared__ float red_s[4];
    const int blk = blockIdx.x, tid = threadIdx.x;
    float s = 0.f;
    const float* dp = deltas + blk * 2048;
    for (int i = tid; i < 2048; i += 256) s += dp[i];
    if (tid < 32) s += partials[blk * 32 + tid];
    #pragma unroll
    for (int m = 1; m < 64; m <<= 1) s += __shfl_xor(s, m, 64);
    if ((tid & 63) == 0) red_s[tid >> 6] = s;
    __syncthreads();
    if (tid == 0) part2[blk] = red_s[0] + red_s[1] + red_s[2] + red_s[3];
}

__global__ void loss_stage2(const float* __restrict__ part2, float* __restrict__ out_loss) {
    const int tid = threadIdx.x;
    float s = part2[tid];
    #pragma unroll
    for (int m = 1; m < 64; m <<= 1) s += __shfl_xor(s, m, 64);
    if (tid == 0) out_loss[0] = 1.25f * (s / (float)NUMEL);
}

extern "C" void kernel_launch(void* const* d_in, const int* in_sizes, int n_in,
                              void* d_out, int out_size, void* d_ws, size_t ws_size,
                              hipStream_t stream) {
    (void)in_sizes; (void)n_in; (void)out_size; (void)ws_size;
    const float* in = (const float*)d_in[0];
    const float* cb = (const float*)d_in[1];
    float* out = (float*)d_out;

    char* ws = (char*)d_ws;
    float* bn       = (float*)(ws + 0);          //    4096 B
    u16*   Bpl      = (u16*)(ws + 4096);         //  262144 B (hi plane only)
    uint2* smallL   = (uint2*)(ws + 528384);     //  262144 B
    int*   fullL    = (int*)(ws + 790528);       //  131072 B
    float* deltas   = (float*)(ws + 921600);     //  524288 B
    float* partials = (float*)(ws + 1445888);    //    8192 B
    float* part2    = (float*)(ws + 1454080);    //     256 B
    int*   cnts     = (int*)(ws + 1454336);      //     128 B

    float* idxf = out + NUMEL + 1;

    prep_cb_kernel<<<4, 256, 0, stream>>>(cb, bn, Bpl, cnts);
    gemm_fused_kernel<<<2048, 256, 0, stream>>>(in, cb, Bpl, bn, out, idxf,
                                                smallL, fullL, cnts, deltas, partials);
    small_rescore_kernel<<<1024, 256, 0, stream>>>(in, cb, bn, smallL, cnts, idxf, out, deltas);
    full_rescore_kernel<<<256, 256, 0, stream>>>(in, cb, bn, fullL, cnts, idxf, out, deltas);
    loss_stage1<<<64, 256, 0, stream>>>(partials, deltas, part2);
    loss_stage2<<<1, 64, 0, stream>>>(part2, out + NUMEL);
}

// Round 11
// 289.330 us; speedup vs baseline: 2.3045x; 2.3045x over previous
//
#include <hip/hip_runtime.h>

typedef unsigned short u16;
typedef __attribute__((ext_vector_type(8))) short bf16x8;
typedef __attribute__((ext_vector_type(4))) float f32x4;

#define K_CB  1024
#define N_ROWS 131072
#define NUMEL (N_ROWS * 128)
#define TAU2 6.0e-4f
#define SMALLCAP 32768
#define FULLCAP  32768

#define GLOAD16(gp, lp) __builtin_amdgcn_global_load_lds( \
    (const __attribute__((address_space(1))) unsigned int*)(gp), \
    (__attribute__((address_space(3))) unsigned int*)(lp), 16, 0, 0)

__device__ __forceinline__ u16 f2bf(float x) {
    union { float f; unsigned int u; } a; a.f = x;
    unsigned int r = a.u + 0x7fffu + ((a.u >> 16) & 1u);
    return (u16)(r >> 16);
}

// ---------- prep codebook: bn + slice-major bf16 HI plane ----------
// Bpl layout: [16 slices][1024 rows][8 bf16]
__global__ void prep_cb_kernel(const float* __restrict__ cb, float* __restrict__ bn,
                               u16* __restrict__ Bpl, int* __restrict__ cnts) {
    int k = blockIdx.x * 256 + threadIdx.x;
    if (blockIdx.x == 0 && threadIdx.x < 2) cnts[threadIdx.x] = 0;
    if (k >= K_CB) return;
    const float4* row4 = reinterpret_cast<const float4*>(cb) + k * 32;
    float s = 0.f;
    #pragma unroll
    for (int i = 0; i < 32; ++i) {
        float4 v = row4[i];
        s = fmaf(v.x, v.x, s); s = fmaf(v.y, v.y, s);
        s = fmaf(v.z, v.z, s); s = fmaf(v.w, v.w, s);
    }
    bn[k] = s;
    const float* rf = cb + k * 128;
    #pragma unroll
    for (int s8 = 0; s8 < 16; ++s8) {
        unsigned int hw[8];
        #pragma unroll
        for (int j = 0; j < 8; ++j) hw[j] = f2bf(rf[s8 * 8 + j]);
        uint4 H;
        H.x = hw[0] | (hw[1] << 16); H.y = hw[2] | (hw[3] << 16);
        H.z = hw[4] | (hw[5] << 16); H.w = hw[6] | (hw[7] << 16);
        *reinterpret_cast<uint4*>(&Bpl[((size_t)s8 * 1024 + k) * 8]) = H;
    }
}

// ---------- fused: transpose+split + hi-plane MFMA GEMM + argmin + candidates + quantize + loss
// r5 structure; K-loop uses counted vmcnt + 2 raw barriers (no per-step vmcnt(0) drain);
// flag emission aggregated to 1 global atomic per list per block.
__launch_bounds__(256, 3)
__global__ void gemm_fused_kernel(const float* __restrict__ in, const float* __restrict__ cb,
                                  const u16* __restrict__ Bpl, const float* __restrict__ bn,
                                  float* __restrict__ out_q, float* __restrict__ idx_out,
                                  uint2* __restrict__ smallL, int* __restrict__ fullL,
                                  int* __restrict__ cnts,
                                  float* __restrict__ deltas, float* __restrict__ partials) {
    __shared__ u16 A_s[16 * 64 * 8];      // 16384 B: [slice][row][8ch] hi plane
    __shared__ u16 Bb[2 * 4 * 256 * 8];   // 32768 B: dbuf x [slice-grp][256 rows][8ch]
    __shared__ float bn_s[K_CB];          // 4096 B
    __shared__ float red_s[4];

    const int tid = threadIdx.x;
    const int w = tid >> 6, lane = tid & 63, g4 = lane >> 4, l15 = lane & 15;
    const int blk = blockIdx.x, n0 = blk * 64;

    // B chunk-0 prefetch (slices 0..3, rows 0..255)
    #pragma unroll
    for (int i = 0; i < 4; ++i) {
        const u16* g = Bpl + (size_t)(w * 1024 + i * 64 + lane) * 8;
        GLOAD16(g, &Bb[(w * 256 + i * 64) * 8]);
    }
    for (int i = tid; i < K_CB; i += 256) bn_s[i] = bn[i];

    // A staging: gather [B,C,D,H,W] transpose, bf16-hi split in regs, b128 writes
    {
        const int base = (n0 >> 14) * (128 * 16384) + (n0 & 16383);
        #pragma unroll
        for (int i = 0; i < 4; ++i) {
            int p = tid + i * 256;            // 0..1023
            int n = p & 63, s = p >> 6;       // slice 0..15
            const float* g = in + base + (size_t)(s * 8) * 16384 + n;
            unsigned int pw[8];
            #pragma unroll
            for (int j = 0; j < 8; ++j) pw[j] = f2bf(g[(size_t)j * 16384]);
            uint4 H;
            H.x = pw[0] | (pw[1] << 16); H.y = pw[2] | (pw[3] << 16);
            H.z = pw[4] | (pw[5] << 16); H.w = pw[6] | (pw[7] << 16);
            *reinterpret_cast<uint4*>(&A_s[(s * 64 + n) * 8]) = H;
        }
    }
    __syncthreads();   // full drain: A_s, bn_s, and B piece 0 all complete

    f32x4 acc[4][4];
    const f32x4 zz = {0.f, 0.f, 0.f, 0.f};
    #pragma unroll
    for (int mi = 0; mi < 4; ++mi)
        #pragma unroll
        for (int ni = 0; ni < 4; ++ni) acc[mi][ni] = zz;

    float b1[16], b2[16]; int i1[16];
    #pragma unroll
    for (int sl = 0; sl < 16; ++sl) { b1[sl] = 3.4e38f; b2[sl] = 3.4e38f; i1[sl] = 0; }

    // 16 k-steps: issue-next, counted vmcnt(4) (piece t+1 stays in flight),
    // barrier1 (piece t visible), ds_read+MFMA, barrier2 (reads done -> reuse safe).
    #pragma unroll
    for (int t = 0; t < 16; ++t) {
        const int chunk = t >> 2, cc = t & 3, buf = t & 1;
        if (t < 15) {
            const int t2 = t + 1, chunk2 = t2 >> 2, cc2 = t2 & 3, nb = t2 & 1;
            #pragma unroll
            for (int i = 0; i < 4; ++i) {
                const u16* g = Bpl + (size_t)((cc2 * 4 + w) * 1024 + chunk2 * 256 + i * 64 + lane) * 8;
                GLOAD16(g, &Bb[((nb * 4 + w) * 256 + i * 64) * 8]);
            }
            asm volatile("s_waitcnt vmcnt(4)" ::: "memory");   // own piece-t loads done
        } else {
            asm volatile("s_waitcnt vmcnt(0)" ::: "memory");
        }
        __builtin_amdgcn_s_barrier();                          // piece t visible to all waves

        bf16x8 af[4], bfr[4];
        #pragma unroll
        for (int mi = 0; mi < 4; ++mi)
            af[mi] = *reinterpret_cast<const bf16x8*>(
                &A_s[((cc * 4 + g4) * 64 + mi * 16 + l15) * 8]);
        #pragma unroll
        for (int ni = 0; ni < 4; ++ni)
            bfr[ni] = *reinterpret_cast<const bf16x8*>(
                &Bb[((buf * 4 + g4) * 256 + w * 64 + ni * 16 + l15) * 8]);
        #pragma unroll
        for (int mi = 0; mi < 4; ++mi)
            #pragma unroll
            for (int ni = 0; ni < 4; ++ni)
                acc[mi][ni] = __builtin_amdgcn_mfma_f32_16x16x32_bf16(
                    af[mi], bfr[ni], acc[mi][ni], 0, 0, 0);

        if (cc == 3) {
            #pragma unroll
            for (int ni = 0; ni < 4; ++ni) {
                int n = chunk * 256 + w * 64 + ni * 16 + l15;
                float bnv = bn_s[n];
                #pragma unroll
                for (int mi = 0; mi < 4; ++mi) {
                    #pragma unroll
                    for (int r = 0; r < 4; ++r) {
                        float s = fmaf(-2.0f, acc[mi][ni][r], bnv);
                        int sl = mi * 4 + r;
                        if (s < b1[sl]) { b2[sl] = b1[sl]; b1[sl] = s; i1[sl] = n; }
                        else if (s < b2[sl]) b2[sl] = s;
                    }
                    acc[mi][ni] = zz;
                }
            }
        }
        asm volatile("s_waitcnt lgkmcnt(0)" ::: "memory");     // all LDS reads of buf retired
        __builtin_amdgcn_s_barrier();                          // safe to overwrite buf next step
    }

    // ---- overlay post-loop arrays onto Bb (dead now; all < 8KB, within buf0) ----
    float* m_b1   = (float*)Bb;            // [4][64]
    float* m_b2   = m_b1 + 256;            // [4][64]
    int*   m_i1   = (int*)(m_b2 + 256);    // [4][64]
    int*   idx_s  = m_i1 + 256;            // [64]
    float* gmin_s = (float*)(idx_s + 64);
    int*   flg_s  = (int*)(gmin_s + 64);
    int*   ccnt_s = flg_s + 64;
    int*   fb_s   = ccnt_s + 64;
    int*   cand_s = fb_s + 64;             // [64][4]
    uint2* sRec_s = (uint2*)(cand_s + 256);// [64]
    int*   fRow_s = (int*)(sRec_s + 64);   // [64]
    int*   aux_s  = fRow_s + 64;           // [4]: sCnt, fCnt, sBase, fBase

    // merge across 16 l15 lanes (per-lane b1/b2/i1 stay intact for emission)
    #pragma unroll
    for (int sl = 0; sl < 16; ++sl) {
        float v1 = b1[sl], v2 = b2[sl]; int ix = i1[sl];
        #pragma unroll
        for (int m = 1; m < 16; m <<= 1) {
            float o1 = __shfl_xor(v1, m, 64);
            int   oi = __shfl_xor(ix, m, 64);
            float o2 = __shfl_xor(v2, m, 64);
            if (o1 < v1 || (o1 == v1 && oi < ix)) { v2 = fminf(v1, o2); v1 = o1; ix = oi; }
            else v2 = fminf(v2, o1);
        }
        if (l15 == 0) {
            int mi = sl >> 2, r = sl & 3;
            int rl = mi * 16 + g4 * 4 + r;
            m_b1[w * 64 + rl] = v1; m_b2[w * 64 + rl] = v2; m_i1[w * 64 + rl] = ix;
        }
    }
    __syncthreads();
    if (tid < 64) {
        float v1 = m_b1[tid], v2 = m_b2[tid]; int ix = m_i1[tid];
        #pragma unroll
        for (int wv = 1; wv < 4; ++wv) {
            float o1 = m_b1[wv * 64 + tid], o2 = m_b2[wv * 64 + tid]; int oi = m_i1[wv * 64 + tid];
            if (o1 < v1 || (o1 == v1 && oi < ix)) { v2 = fminf(v1, o2); v1 = o1; ix = oi; }
            else v2 = fminf(v2, o1);
        }
        idx_s[tid] = ix;
        idx_out[n0 + tid] = (float)ix;
        deltas[n0 + tid] = 0.f;
        gmin_s[tid] = v1;
        flg_s[tid] = (v2 - v1 <= TAU2) ? 1 : 0;
        ccnt_s[tid] = 0;
        fb_s[tid] = 0;
        if (tid < 2) aux_s[tid] = 0;   // sCnt, fCnt
    }
    __syncthreads();

    // candidate emission: each (w,l15) bucket offers its best if within TAU2 of row min
    #pragma unroll
    for (int sl = 0; sl < 16; ++sl) {
        int mi = sl >> 2, r = sl & 3;
        int rl = mi * 16 + g4 * 4 + r;
        if (flg_s[rl]) {
            float g = gmin_s[rl];
            if (b1[sl] - g <= TAU2) {
                int p = atomicAdd(&ccnt_s[rl], 1);
                if (p < 4) cand_s[rl * 4 + p] = i1[sl]; else fb_s[rl] = 1;
            }
            if (b2[sl] - g <= TAU2) fb_s[rl] = 1;  // can't bound 3rd-in-bucket
        }
    }
    __syncthreads();

    // classify flagged rows into LDS lists (block-local atomics only)
    if (tid < 64 && flg_s[tid]) {
        int nc = ccnt_s[tid];
        int row = n0 + tid;
        if (!fb_s[tid] && nc >= 2) {
            unsigned long long key = (unsigned long long)row |
                                     ((unsigned long long)nc << 20);
            for (int j = 0; j < nc; ++j)
                key |= (unsigned long long)(cand_s[tid * 4 + j] & 1023) << (24 + 10 * j);
            int p = atomicAdd(&aux_s[0], 1);
            uint2 rec; rec.x = (unsigned)key; rec.y = (unsigned)(key >> 32);
            sRec_s[p] = rec;
        } else if (fb_s[tid]) {
            int q = atomicAdd(&aux_s[1], 1);
            fRow_s[q] = row;
        }
    }
    __syncthreads();
    // one global atomic per non-empty list per block
    if (tid == 0)  aux_s[2] = (aux_s[0] > 0) ? atomicAdd(&cnts[0], aux_s[0]) : 0;
    if (tid == 64) aux_s[3] = (aux_s[1] > 0) ? atomicAdd(&cnts[1], aux_s[1]) : 0;
    __syncthreads();
    if (tid < aux_s[0]) {
        int p = aux_s[2] + tid;
        if (p < SMALLCAP) smallL[p] = sRec_s[tid];
        else {  // overflow -> route to full list (rare)
            int q = atomicAdd(&cnts[1], 1);
            if (q < FULLCAP) fullL[q] = (int)(sRec_s[tid].x & 131071u);
        }
    }
    if (tid >= 64 && tid < 128 && (tid - 64) < aux_s[1]) {
        int p = aux_s[3] + (tid - 64);
        if (p < FULLCAP) fullL[p] = fRow_s[tid - 64];
    }
    __syncthreads();

    // fused quantize + straight-through + loss partial (linear flat layout)
    float acc_l = 0.f;
    const float4* cb4 = reinterpret_cast<const float4*>(cb);
    const float4* in4 = reinterpret_cast<const float4*>(in);
    float4* out4 = reinterpret_cast<float4*>(out_q);
    #pragma unroll
    for (int i = 0; i < 8; ++i) {
        int idx = tid + i * 256;
        int row = idx >> 5;
        int c4 = idx & 31;
        int kq = idx_s[row];
        float4 q = cb4[kq * 32 + c4];
        float4 x = in4[(size_t)(n0 + row) * 32 + c4];
        float4 d, o;
        d.x = q.x - x.x; d.y = q.y - x.y; d.z = q.z - x.z; d.w = q.w - x.w;
        o.x = x.x + d.x; o.y = x.y + d.y; o.z = x.z + d.z; o.w = x.w + d.w;
        out4[(size_t)(n0 + row) * 32 + c4] = o;
        acc_l += d.x * d.x; acc_l += d.y * d.y; acc_l += d.z * d.z; acc_l += d.w * d.w;
    }
    #pragma unroll
    for (int m = 1; m < 64; m <<= 1) acc_l += __shfl_xor(acc_l, m, 64);
    if (lane == 0) red_s[w] = acc_l;
    __syncthreads();
    if (tid == 0) partials[blk] = red_s[0] + red_s[1] + red_s[2] + red_s[3];
}

// ---------- common patch helper (wave-level) ----------
__device__ __forceinline__ void patch_row(const float* __restrict__ in,
                                          const float* __restrict__ cb,
                                          float* __restrict__ idx_out,
                                          float* __restrict__ out_q,
                                          float* __restrict__ deltas,
                                          int row, int k_new, int lane) {
    int k_old = (int)idx_out[row];
    if (k_new == k_old) return;
    if (lane == 0) idx_out[row] = (float)k_new;
    float dd = 0.f;
    if (lane < 32) {
        const float4* in4 = reinterpret_cast<const float4*>(in);
        const float4* cb4 = reinterpret_cast<const float4*>(cb);
        float4* out4 = reinterpret_cast<float4*>(out_q);
        float4 x = in4[(size_t)row * 32 + lane];
        float4 qn = cb4[(size_t)k_new * 32 + lane];
        float4 qo = cb4[(size_t)k_old * 32 + lane];
        float4 dn, dl, o;
        dn.x = qn.x - x.x; dn.y = qn.y - x.y; dn.z = qn.z - x.z; dn.w = qn.w - x.w;
        o.x = x.x + dn.x; o.y = x.y + dn.y; o.z = x.z + dn.z; o.w = x.w + dn.w;
        out4[(size_t)row * 32 + lane] = o;
        dl.x = qo.x - x.x; dl.y = qo.y - x.y; dl.z = qo.z - x.z; dl.w = qo.w - x.w;
        dd = dn.x * dn.x + dn.y * dn.y + dn.z * dn.z + dn.w * dn.w
           - (dl.x * dl.x + dl.y * dl.y + dl.z * dl.z + dl.w * dl.w);
    }
    #pragma unroll
    for (int m = 1; m < 64; m <<= 1) dd += __shfl_xor(dd, m, 64);
    if (lane == 0) deltas[row] = dd;
}

// ---------- small rescore: one wave per record, <=4 candidates, exact arithmetic ----------
__global__ void small_rescore_kernel(const float* __restrict__ in, const float* __restrict__ cb,
                                     const float* __restrict__ bn, const uint2* __restrict__ recs,
                                     const int* __restrict__ cnts, float* __restrict__ idx_out,
                                     float* __restrict__ out_q, float* __restrict__ deltas) {
    __shared__ float xls[4][128];
    const int tid = threadIdx.x, wv = tid >> 6, lane = tid & 63;
    int ns = cnts[0]; if (ns > SMALLCAP) ns = SMALLCAP;
    float* xl = xls[wv];
    for (int f = blockIdx.x * 4 + wv; f < ns; f += gridDim.x * 4) {
        uint2 rc = recs[f];
        unsigned long long key = ((unsigned long long)rc.y << 32) | (unsigned long long)rc.x;
        int row = (int)(key & 131071ull);
        int nc = (int)((key >> 20) & 7ull);
        int ck = (lane < 4) ? (int)((key >> (24 + 10 * lane)) & 1023ull) : 0;
        const float* bp = in + (size_t)(row >> 14) * 2097152 + (row & 16383);
        xl[2 * lane]     = bp[(size_t)(2 * lane) * 16384];
        xl[2 * lane + 1] = bp[(size_t)(2 * lane + 1) * 16384];
        asm volatile("s_waitcnt vmcnt(0) lgkmcnt(0)" ::: "memory");
        float xn = 0.f;
        for (int c = 0; c < 128; ++c) { float v = xl[c]; xn = fmaf(v, v, xn); }
        float s = 3.4e38f; int kk = 0x7fffffff;
        if (lane < nc) {
            const float4* cr = reinterpret_cast<const float4*>(cb + (size_t)ck * 128);
            float dot = 0.f;
            #pragma unroll
            for (int c4 = 0; c4 < 32; ++c4) {
                float4 bv = cr[c4];
                float4 xv = *reinterpret_cast<const float4*>(&xl[c4 * 4]);
                dot = fmaf(xv.x, bv.x, dot); dot = fmaf(xv.y, bv.y, dot);
                dot = fmaf(xv.z, bv.z, dot); dot = fmaf(xv.w, bv.w, dot);
            }
            float t1 = xn + bn[ck];
            s = fmaf(-2.0f, dot, t1);
            kk = ck;
        }
        #pragma unroll
        for (int m = 1; m < 4; m <<= 1) {
            float os = __shfl_xor(s, m, 64);
            int ok = __shfl_xor(kk, m, 64);
            if (os < s || (os == s && ok < kk)) { s = os; kk = ok; }
        }
        int k_new = __shfl(kk, 0, 64);
        patch_row(in, cb, idx_out, out_q, deltas, row, k_new, lane);
    }
}

// ---------- full rescore fallback: one wave per row, exact arithmetic ----------
__global__ void full_rescore_kernel(const float* __restrict__ in, const float* __restrict__ cb,
                                    const float* __restrict__ bn, const int* __restrict__ fullL,
                                    const int* __restrict__ cnts, float* __restrict__ idx_out,
                                    float* __restrict__ out_q, float* __restrict__ deltas) {
    __shared__ float xls[4][128];
    const int tid = threadIdx.x, wv = tid >> 6, lane = tid & 63;
    int nf = cnts[1]; if (nf > FULLCAP) nf = FULLCAP;
    float* xl = xls[wv];
    for (int f = blockIdx.x * 4 + wv; f < nf; f += gridDim.x * 4) {
        int row = fullL[f];
        const float* bp = in + (size_t)(row >> 14) * 2097152 + (row & 16383);
        xl[2 * lane]     = bp[(size_t)(2 * lane) * 16384];
        xl[2 * lane + 1] = bp[(size_t)(2 * lane + 1) * 16384];
        asm volatile("s_waitcnt vmcnt(0) lgkmcnt(0)" ::: "memory");
        float xn = 0.f;
        for (int c = 0; c < 128; ++c) { float v = xl[c]; xn = fmaf(v, v, xn); }
        float best = 3.4e38f; int bi = 0x7fffffff;
        for (int j = 0; j < 16; ++j) {
            int k = j * 64 + lane;
            const float4* cr = reinterpret_cast<const float4*>(cb + (size_t)k * 128);
            float dot = 0.f;
            #pragma unroll
            for (int c4 = 0; c4 < 32; ++c4) {
                float4 bv = cr[c4];
                float4 xv = *reinterpret_cast<const float4*>(&xl[c4 * 4]);
                dot = fmaf(xv.x, bv.x, dot); dot = fmaf(xv.y, bv.y, dot);
                dot = fmaf(xv.z, bv.z, dot); dot = fmaf(xv.w, bv.w, dot);
            }
            float t1 = xn + bn[k];
            float s = fmaf(-2.0f, dot, t1);
            if (s < best || (s == best && k < bi)) { best = s; bi = k; }
        }
        #pragma unroll
        for (int m = 1; m < 64; m <<= 1) {
            float os = __shfl_xor(best, m, 64);
            int ok = __shfl_xor(bi, m, 64);
            if (os < best || (os == best && ok < bi)) { best = os; bi = ok; }
        }
        int k_new = __shfl(bi, 0, 64);
        patch_row(in, cb, idx_out, out_q, deltas, row, k_new, lane);
    }
}

// ---------- deterministic 2-stage loss reduce ----------
__global__ void loss_stage1(const float* __restrict__ partials, const float* __restrict__ deltas,
                            float* __restrict__ part2) {
    __shared__ float red_s[4];
    const int blk = blockIdx.x, tid = threadIdx.x;
    float s = 0.f;
    const float* dp = deltas + blk * 2048;
    for (int i = tid; i < 2048; i += 256) s += dp[i];
    if (tid < 32) s += partials[blk * 32 + tid];
    #pragma unroll
    for (int m = 1; m < 64; m <<= 1) s += __shfl_xor(s, m, 64);
    if ((tid & 63) == 0) red_s[tid >> 6] = s;
    __syncthreads();
    if (tid == 0) part2[blk] = red_s[0] + red_s[1] + red_s[2] + red_s[3];
}

__global__ void loss_stage2(const float* __restrict__ part2, float* __restrict__ out_loss) {
    const int tid = threadIdx.x;
    float s = part2[tid];
    #pragma unroll
    for (int m = 1; m < 64; m <<= 1) s += __shfl_xor(s, m, 64);
    if (tid == 0) out_loss[0] = 1.25f * (s / (float)NUMEL);
}

extern "C" void kernel_launch(void* const* d_in, const int* in_sizes, int n_in,
                              void* d_out, int out_size, void* d_ws, size_t ws_size,
                              hipStream_t stream) {
    (void)in_sizes; (void)n_in; (void)out_size; (void)ws_size;
    const float* in = (const float*)d_in[0];
    const float* cb = (const float*)d_in[1];
    float* out = (float*)d_out;

    char* ws = (char*)d_ws;
    float* bn       = (float*)(ws + 0);          //    4096 B
    u16*   Bpl      = (u16*)(ws + 4096);         //  262144 B (hi plane only)
    uint2* smallL   = (uint2*)(ws + 528384);     //  262144 B
    int*   fullL    = (int*)(ws + 790528);       //  131072 B
    float* deltas   = (float*)(ws + 921600);     //  524288 B
    float* partials = (float*)(ws + 1445888);    //    8192 B
    float* part2    = (float*)(ws + 1454080);    //     256 B
    int*   cnts     = (int*)(ws + 1454336);      //     128 B

    float* idxf = out + NUMEL + 1;

    prep_cb_kernel<<<4, 256, 0, stream>>>(cb, bn, Bpl, cnts);
    gemm_fused_kernel<<<2048, 256, 0, stream>>>(in, cb, Bpl, bn, out, idxf,
                                                smallL, fullL, cnts, deltas, partials);
    small_rescore_kernel<<<1024, 256, 0, stream>>>(in, cb, bn, smallL, cnts, idxf, out, deltas);
    full_rescore_kernel<<<256, 256, 0, stream>>>(in, cb, bn, fullL, cnts, idxf, out, deltas);
    loss_stage1<<<64, 256, 0, stream>>>(partials, deltas, part2);
    loss_stage2<<<1, 64, 0, stream>>>(part2, out + NUMEL);
}